// Round 2
// baseline (265.572 us; speedup 1.0000x reference)
//
#include <hip/hip_runtime.h>
#include <hip/hip_bf16.h>

// DifferentiableXGB: logits = epilogue(x @ W1^T + b1)
//   split[b,n] = sum_d x[b,d]*W1[n,d] + b1[n]          (n = t*4+k, N=400)
//   S[b,t] = sum_k split[b,t,k]
//   logits[b,j] = sum_t fw[t]*S[b,t]*sum_k sigmoid(split[b,t,k])*fc_w[j,k] + fc_b[j]
//
// V9 = V8 restructured for 2 INDEPENDENT blocks per CU.
// R8 post-mortem: V8's scratch fix confirmed (WRITE 50.8->4 MB) but dur only
// 105->88 us. MFMA-busy time (11.5% x 88us = 10.1us) == compute floor, so the
// MFMA pipe is fine; the kernel idles ~80% of the time. Cause: grid=256 =
// 1 block/CU, all 10 waves chained to one __syncthreads per chunk, which
// drains vmcnt(0) (incl. the just-issued c+1 prefetch) -> whole-CU idle for
// HBM/L2 latency every chunk, nothing to overlap with.
// V9: BM 128->64, BK 64->32, THREADS 640->320 (5 waves, nf=0..4, MT=4),
// grid 512. LDS 137->62 KB/block -> 2 blocks co-resident per CU; one block
// computes while the other drains its barrier. mh-split removed -> B-tile
// LDS reads no longer duplicated across halves.
//   - XOR-rotate swizzle for 32-short rows: phys_sub=(sub+(row>>1))&3
//     (rows 0..7 hit 8 distinct bank-quads -> 2-way = free).
//   - A staged fused from fp32 x (read once, cvt in regs, tid<256 slot).
//   - B (W1 bf16 in ws) via global_load_lds dwordx4, 25 dma/chunk, 5/wave.
//   - launch_bounds(320,3): cap 168 regs incl AGPR (need ~150).

typedef __bf16 bf16x8 __attribute__((ext_vector_type(8)));
typedef float f32x4 __attribute__((ext_vector_type(4)));

#define B_ROWS 32768
#define D_DIM  1024
#define N_COLS 400
#define BM     64
#define BK     32
#define NCHUNK 32          // 1024 / 32
#define THREADS 320        // 5 waves: nf = wave (0..4)
#define NTPW 5             // n-tiles (16 wide) per wave
#define MT   4             // m-tiles (16 tall) per wave (all 64 rows)

__device__ __forceinline__ unsigned short f2bf(float f) {
    unsigned int u = __float_as_uint(f);
    u += 0x7FFFu + ((u >> 16) & 1u);   // RTNE
    return (unsigned short)(u >> 16);
}
__device__ __forceinline__ unsigned int pk2(float a, float b) {
    return (unsigned int)f2bf(a) | ((unsigned int)f2bf(b) << 16);
}
__device__ __forceinline__ uint4 cvt8u(float4 a, float4 b) {
    uint4 u;
    u.x = pk2(a.x, a.y); u.y = pk2(a.z, a.w);
    u.z = pk2(b.x, b.y); u.w = pk2(b.z, b.w);
    return u;
}
__device__ __forceinline__ bf16x8 cvt8(float4 a, float4 b) {
    return __builtin_bit_cast(bf16x8, cvt8u(a, b));
}

// tiny: W1 fp32 -> bf16 (1.6 MB)
__global__ void cvt_f32_bf16_kernel(const float* __restrict__ in,
                                    unsigned short* __restrict__ out) {
    size_t i = ((size_t)blockIdx.x * 256 + threadIdx.x) * 8;
    float4 v0 = *reinterpret_cast<const float4*>(in + i);
    float4 v1 = *reinterpret_cast<const float4*>(in + i + 4);
    *reinterpret_cast<uint4*>(out + i) = cvt8u(v0, v1);
}

// async 16B/lane global->LDS; lds dest = wave-uniform base + lane*16 (HW)
__device__ __forceinline__ void gl_lds16(const unsigned short* g,
                                         unsigned short* l) {
    __builtin_amdgcn_global_load_lds(
        (const __attribute__((address_space(1))) unsigned int*)g,
        (__attribute__((address_space(3))) unsigned int*)l,
        16, 0, 0);
}

// ---- macro machinery: every hot value is an individually named register ----
#define FOR_N_(OP, m) OP(m,0) OP(m,1) OP(m,2) OP(m,3) OP(m,4)
#define FOR_MN(OP) FOR_N_(OP,0) FOR_N_(OP,1) FOR_N_(OP,2) FOR_N_(OP,3)

#define DECL_ACC(m,n) f32x4 acc##m##n = {};
#define MFMA_MN(m,n) acc##m##n = __builtin_amdgcn_mfma_f32_16x16x32_bf16( \
        afr##m, bfr##n, acc##m##n, 0, 0, 0);

// MODE 0: A fp32 (fused cvt), B bf16 (ws). MODE 2: both fp32, plain loop.
template <int MODE>
__global__ __launch_bounds__(THREADS, 3) void xgb_v9(
    const float* __restrict__ x,
    const void*  __restrict__ b_any,
    const float* __restrict__ b1,
    const float* __restrict__ fw,
    const float* __restrict__ fcw,      // [2,4]
    const float* __restrict__ fcb,      // [2]
    float* __restrict__ out)            // [B,2]
{
    // double-buffered tiles; rows of 32 shorts (64 B), sub-chunk = 8 shorts
    // (16 B), 4 subs/row; swizzle: phys_sub = (sub + (row>>1)) & 3
    __shared__ __align__(16) unsigned short Abuf[2][BM * BK];       // 8 KB
    __shared__ __align__(16) unsigned short Bbuf[2][N_COLS * BK];   // 50 KB
    __shared__ float Pbuf[BM * NTPW * 2];                           // 2.5 KB

    const int tid  = threadIdx.x;
    const int wave = tid >> 6;          // 0..4
    const int lane = tid & 63;
    const int quad = lane >> 4;
    const int l15  = lane & 15;
    const int nf   = wave;              // n fifth: 5 tiles each
    const int row0 = blockIdx.x * BM;

    FOR_MN(DECL_ACC)                    // acc00..acc34, 20 x f32x4

    if (MODE == 0) {
        const unsigned short* w1b = (const unsigned short*)b_any;

        // ---- B staging: 25 dma/chunk, 5 per wave. stage s covers buffer
        // rows 16s..16s+15 (1024 B). lane i -> row 16s+(i>>2), phys slot
        // i&3; it fetches the logical sub that belongs at that slot:
        // c = ((i&3) - (row>>1)) & 3.
#define BDECL(t) const unsigned short* bsrc##t; int bdst##t; \
        { const int s_ = wave + 5 * (t); const int rb_ = s_ * 16 + (lane >> 2); \
          const int cc_ = ((lane & 3) - (rb_ >> 1)) & 3; \
          bsrc##t = w1b + (size_t)rb_ * D_DIM + cc_ * 8; \
          bdst##t = s_ * 512; }                    // shorts
        BDECL(0) BDECL(1) BDECL(2) BDECL(3) BDECL(4)

        // ---- A staging: 64 rows x 4 subs = 256 sub-chunks/chunk. STATIC:
        // thread tid<256 owns sub-chunk tid (waves 0..3, wave-uniform guard,
        // compile-time indices -> register-resident).
        const int r0a = tid >> 2, c0a = tid & 3;
        const bool doA = (tid < 256);
        const float* asrc0 = x + (size_t)(row0 + r0a) * D_DIM + c0a * 8;
        const int adst0 = r0a * 32 + ((c0a + (r0a >> 1)) & 3) * 8;   // swizzled
        float4 areg00, areg01;

#define LOADA(kc) do { if (doA) { \
        areg00 = *reinterpret_cast<const float4*>(asrc0 + (kc));     \
        areg01 = *reinterpret_cast<const float4*>(asrc0 + (kc) + 4); \
        } } while (0)

#define WRITEA(Ab) do { if (doA) \
        *reinterpret_cast<uint4*>((Ab) + adst0) = cvt8u(areg00, areg01); \
        } while (0)

#define STAGEB(kc, Bb) do { \
        gl_lds16(bsrc0 + (kc), (Bb) + bdst0); \
        gl_lds16(bsrc1 + (kc), (Bb) + bdst1); \
        gl_lds16(bsrc2 + (kc), (Bb) + bdst2); \
        gl_lds16(bsrc3 + (kc), (Bb) + bdst3); \
        gl_lds16(bsrc4 + (kc), (Bb) + bdst4); } while (0)

#define LOAD_AFR(m) { const int row_ = (m) * 16 + l15; \
        const int p_ = (quad + (row_ >> 1)) & 3; \
        afr##m = *reinterpret_cast<const bf16x8*>(Ab_ + row_ * 32 + p_ * 8); }
#define LOAD_BFR(n) { const int row_ = (nf * NTPW + (n)) * 16 + l15; \
        const int p_ = (quad + (row_ >> 1)) & 3; \
        bfr##n = *reinterpret_cast<const bf16x8*>(Bb_ + row_ * 32 + p_ * 8); }

        // prologue: stage chunk 0 into buffer 0
        LOADA(0);
        STAGEB(0, Bbuf[0]);
        WRITEA(Abuf[0]);

        #pragma unroll 1
        for (int c = 0; c < NCHUNK; ++c) {
            const int cur = c & 1;
            const unsigned short* Ab_ = Abuf[cur];
            const unsigned short* Bb_ = Bbuf[cur];
            __syncthreads();            // drains chunk-c staging; buf^1 free
            if (c + 1 < NCHUNK) {
                LOADA((c + 1) * BK);                 // globals fly over compute
                STAGEB((c + 1) * BK, Bbuf[1 - cur]); // dma flies over compute
            }
            {
                bf16x8 afr0, afr1, afr2, afr3;
                bf16x8 bfr0, bfr1, bfr2, bfr3, bfr4;
                LOAD_AFR(0) LOAD_AFR(1) LOAD_AFR(2) LOAD_AFR(3)
                LOAD_BFR(0) LOAD_BFR(1) LOAD_BFR(2) LOAD_BFR(3) LOAD_BFR(4)
                FOR_MN(MFMA_MN)
            }
            if (c + 1 < NCHUNK) WRITEA(Abuf[1 - cur]);  // cvt after compute
        }
    } else {
        // fallback: both fp32, plain loop (correctness insurance, no ws)
        const float* af = x + (size_t)(row0 + l15) * D_DIM + quad * 8;
        const float* bf32 = (const float*)b_any
                          + (size_t)((nf * NTPW) * 16 + l15) * D_DIM + quad * 8;
        for (int step = 0; step < 32; ++step) {
            const int off = step * 32;
            bf16x8 afr0, afr1, afr2, afr3;
            bf16x8 bfr0, bfr1, bfr2, bfr3, bfr4;
#define LOAD_AFR2(m) { \
            float4 a0_ = *reinterpret_cast<const float4*>(af + (size_t)(m) * 16 * D_DIM + off); \
            float4 a1_ = *reinterpret_cast<const float4*>(af + (size_t)(m) * 16 * D_DIM + off + 4); \
            afr##m = cvt8(a0_, a1_); }
#define LOAD_BFR2(n) { \
            float4 b0_ = *reinterpret_cast<const float4*>(bf32 + (size_t)(n) * 16 * D_DIM + off); \
            float4 b1_ = *reinterpret_cast<const float4*>(bf32 + (size_t)(n) * 16 * D_DIM + off + 4); \
            bfr##n = cvt8(b0_, b1_); }
            LOAD_AFR2(0) LOAD_AFR2(1) LOAD_AFR2(2) LOAD_AFR2(3)
            LOAD_BFR2(0) LOAD_BFR2(1) LOAD_BFR2(2) LOAD_BFR2(3) LOAD_BFR2(4)
            FOR_MN(MFMA_MN)
        }
    }

    // ---- epilogue ----
    // C/D layout: col = l15 (within tile), row = quad*4 + reg   [m89/m91]
    const float fcw0 = fcw[l15 & 3];        // fc_w[0][k], k = col&3
    const float fcw1 = fcw[4 + (l15 & 3)];  // fc_w[1][k]

#define PRE_N(n) \
    const float bias##n = b1[(nf * NTPW + (n)) * 16 + l15]; \
    const float tw##n   = fw[((nf * NTPW + (n)) * 16 + l15) >> 2];
    PRE_N(0) PRE_N(1) PRE_N(2) PRE_N(3) PRE_N(4)

    // per (m,r): q = sum over n of fw[t]*sigmoid(split)*S ; then 16-lane sum.
    // k-sum S: lanes ^1,^2 (l15 bits 0-1 are k within tree).
#define EPI_TERM(m,r,n) { \
        const float split_ = acc##m##n[r] + bias##n; \
        float s_ = split_; \
        s_ += __shfl_xor(s_, 1); \
        s_ += __shfl_xor(s_, 2); \
        const float leaf_ = 1.0f / (1.0f + __expf(-split_)); \
        const float val_ = tw##n * leaf_ * s_; \
        q0 += val_ * fcw0; q1 += val_ * fcw1; }

#define EPI_ONE(m,r) { \
        float q0 = 0.f, q1 = 0.f; \
        EPI_TERM(m,r,0) EPI_TERM(m,r,1) EPI_TERM(m,r,2) \
        EPI_TERM(m,r,3) EPI_TERM(m,r,4) \
        q0 += __shfl_xor(q0, 1); q0 += __shfl_xor(q0, 2); \
        q0 += __shfl_xor(q0, 4); q0 += __shfl_xor(q0, 8); \
        q1 += __shfl_xor(q1, 1); q1 += __shfl_xor(q1, 2); \
        q1 += __shfl_xor(q1, 4); q1 += __shfl_xor(q1, 8); \
        const int row_ = (m) * 16 + quad * 4 + (r);           /* 0..63 */ \
        if (l15 == 0) Pbuf[(row_ * NTPW + nf) * 2 + 0] = q0; \
        if (l15 == 1) Pbuf[(row_ * NTPW + nf) * 2 + 1] = q1; }

#define EPI_M(m) EPI_ONE(m,0) EPI_ONE(m,1) EPI_ONE(m,2) EPI_ONE(m,3)
    EPI_M(0) EPI_M(1) EPI_M(2) EPI_M(3)

    __syncthreads();

    if (tid < 2 * BM) {
        const int r = tid >> 1, j = tid & 1;
        float s = fcb[j];
        #pragma unroll
        for (int w = 0; w < NTPW; ++w)
            s += Pbuf[(r * NTPW + w) * 2 + j];
        out[(row0 + r) * 2 + j] = s;
    }
}

extern "C" void kernel_launch(void* const* d_in, const int* in_sizes, int n_in,
                              void* d_out, int out_size, void* d_ws, size_t ws_size,
                              hipStream_t stream) {
    const float* x   = (const float*)d_in[0];
    const float* W1  = (const float*)d_in[1];
    const float* b1  = (const float*)d_in[2];
    const float* fw  = (const float*)d_in[3];
    const float* fcw = (const float*)d_in[4];
    const float* fcb = (const float*)d_in[5];
    float* out = (float*)d_out;

    const size_t w1_elems = (size_t)N_COLS * D_DIM;   // 409,600
    if (ws_size >= w1_elems * sizeof(unsigned short)) {
        unsigned short* w1b = (unsigned short*)d_ws;
        cvt_f32_bf16_kernel<<<(int)(w1_elems / 2048), 256, 0, stream>>>(W1, w1b);
        xgb_v9<0><<<B_ROWS / BM, THREADS, 0, stream>>>(
            x, (const void*)w1b, b1, fw, fcw, fcb, out);
    } else {
        xgb_v9<2><<<B_ROWS / BM, THREADS, 0, stream>>>(
            x, (const void*)W1, b1, fw, fcw, fcb, out);
    }
}

// Round 3
// 259.451 us; speedup vs baseline: 1.0236x; 1.0236x over previous
//
#include <hip/hip_runtime.h>
#include <hip/hip_bf16.h>

// DifferentiableXGB: logits = epilogue(x @ W1^T + b1)
//   split[b,n] = sum_d x[b,d]*W1[n,d] + b1[n]          (n = t*4+k, N=400)
//   S[b,t] = sum_k split[b,t,k]
//   logits[b,j] = sum_t fw[t]*S[b,t]*sum_k sigmoid(split[b,t,k])*fc_w[j,k] + fc_b[j]
//
// V11 = V9 with B staging converted from global_load_lds DMA to REG-STAGED
// T14 (issue-early global->reg, write-late ds_write_b128).
// R9 post-mortem: V9 regressed 88->120us; occupancy 14% shows the 2nd block
// never co-resided (160 regs/wave blocks 3-waves/SIMD placement), and
// doubling the chunk count doubled the barrier-drain count. Root-cause
// theory for the ~13k cy/chunk stall (V8): the global_load_lds DMA queue
// (25-50 instrs/CU/chunk) drains at the barrier with no throughput to match
// — known-good kernels use <=2 DMAs/wave; HipKittens reg-stages instead.
// V11: after each barrier, issue 5 dwordx4 B-loads (+A loads) to NAMED regs;
// compute(cur) overlaps the flight time; then 5 swizzled ds_write_b128 into
// buf^1. Barrier now only orders LDS writes vs reads.
//   - 5 waves (320 thr), BM=64, BK=32, grid 512, MT=4, NT=5.
//   - launch_bounds(320,2): cap 256 regs, no forced spills (~190 used).
//   - XOR-rotate swizzle phys_sub=(sub+(row>>1))&3 on both A and B paths.

typedef __bf16 bf16x8 __attribute__((ext_vector_type(8)));
typedef float f32x4 __attribute__((ext_vector_type(4)));

#define B_ROWS 32768
#define D_DIM  1024
#define N_COLS 400
#define BM     64
#define BK     32
#define NCHUNK 32          // 1024 / 32
#define THREADS 320        // 5 waves: nf = wave (0..4)
#define NTPW 5             // n-tiles (16 wide) per wave
#define MT   4             // m-tiles (16 tall) per wave (all 64 rows)

__device__ __forceinline__ unsigned short f2bf(float f) {
    unsigned int u = __float_as_uint(f);
    u += 0x7FFFu + ((u >> 16) & 1u);   // RTNE
    return (unsigned short)(u >> 16);
}
__device__ __forceinline__ unsigned int pk2(float a, float b) {
    return (unsigned int)f2bf(a) | ((unsigned int)f2bf(b) << 16);
}
__device__ __forceinline__ uint4 cvt8u(float4 a, float4 b) {
    uint4 u;
    u.x = pk2(a.x, a.y); u.y = pk2(a.z, a.w);
    u.z = pk2(b.x, b.y); u.w = pk2(b.z, b.w);
    return u;
}
__device__ __forceinline__ bf16x8 cvt8(float4 a, float4 b) {
    return __builtin_bit_cast(bf16x8, cvt8u(a, b));
}

// tiny: W1 fp32 -> bf16 (1.6 MB)
__global__ void cvt_f32_bf16_kernel(const float* __restrict__ in,
                                    unsigned short* __restrict__ out) {
    size_t i = ((size_t)blockIdx.x * 256 + threadIdx.x) * 8;
    float4 v0 = *reinterpret_cast<const float4*>(in + i);
    float4 v1 = *reinterpret_cast<const float4*>(in + i + 4);
    *reinterpret_cast<uint4*>(out + i) = cvt8u(v0, v1);
}

// ---- macro machinery: every hot value is an individually named register ----
#define FOR_N_(OP, m) OP(m,0) OP(m,1) OP(m,2) OP(m,3) OP(m,4)
#define FOR_MN(OP) FOR_N_(OP,0) FOR_N_(OP,1) FOR_N_(OP,2) FOR_N_(OP,3)

#define DECL_ACC(m,n) f32x4 acc##m##n = {};
#define MFMA_MN(m,n) acc##m##n = __builtin_amdgcn_mfma_f32_16x16x32_bf16( \
        afr##m, bfr##n, acc##m##n, 0, 0, 0);

// MODE 0: A fp32 (fused cvt), B bf16 (ws). MODE 2: both fp32, plain loop.
template <int MODE>
__global__ __launch_bounds__(THREADS, 2) void xgb_v11(
    const float* __restrict__ x,
    const void*  __restrict__ b_any,
    const float* __restrict__ b1,
    const float* __restrict__ fw,
    const float* __restrict__ fcw,      // [2,4]
    const float* __restrict__ fcb,      // [2]
    float* __restrict__ out)            // [B,2]
{
    // double-buffered tiles; rows of 32 shorts (64 B), sub-chunk = 8 shorts
    // (16 B), 4 subs/row; swizzle: phys_sub = (sub + (row>>1)) & 3
    __shared__ __align__(16) unsigned short Abuf[2][BM * BK];       // 8 KB
    __shared__ __align__(16) unsigned short Bbuf[2][N_COLS * BK];   // 50 KB
    __shared__ float Pbuf[BM * NTPW * 2];                           // 2.5 KB

    const int tid  = threadIdx.x;
    const int wave = tid >> 6;          // 0..4
    const int lane = tid & 63;
    const int quad = lane >> 4;
    const int l15  = lane & 15;
    const int nf   = wave;              // n fifth: 5 tiles each
    const int row0 = blockIdx.x * BM;

    FOR_MN(DECL_ACC)                    // acc00..acc34, 20 x f32x4

    if (MODE == 0) {
        const unsigned short* w1b = (const unsigned short*)b_any;

        // ---- B staging (reg-staged, T14): B tile = 400 rows x 4 subs =
        // 1600 subs of 16B; thread tid owns u = tid + 320*j (j=0..4,
        // compile-time -> named breg_j, register-resident).
#define BSDECL(j) const unsigned short* pbs##j; int bds##j; \
        { const int u_ = tid + 320 * (j); \
          const int br_ = u_ >> 2; const int bs_ = u_ & 3; \
          pbs##j = w1b + (size_t)br_ * D_DIM + bs_ * 8; \
          bds##j = br_ * 32 + ((bs_ + (br_ >> 1)) & 3) * 8; }   // swizzled
        BSDECL(0) BSDECL(1) BSDECL(2) BSDECL(3) BSDECL(4)
        uint4 breg0, breg1, breg2, breg3, breg4;

#define BLOAD(kc) do { \
        breg0 = *reinterpret_cast<const uint4*>(pbs0 + (kc)); \
        breg1 = *reinterpret_cast<const uint4*>(pbs1 + (kc)); \
        breg2 = *reinterpret_cast<const uint4*>(pbs2 + (kc)); \
        breg3 = *reinterpret_cast<const uint4*>(pbs3 + (kc)); \
        breg4 = *reinterpret_cast<const uint4*>(pbs4 + (kc)); } while (0)

#define BWRITE(Bb) do { \
        *reinterpret_cast<uint4*>((Bb) + bds0) = breg0; \
        *reinterpret_cast<uint4*>((Bb) + bds1) = breg1; \
        *reinterpret_cast<uint4*>((Bb) + bds2) = breg2; \
        *reinterpret_cast<uint4*>((Bb) + bds3) = breg3; \
        *reinterpret_cast<uint4*>((Bb) + bds4) = breg4; } while (0)

        // ---- A staging: 64 rows x 4 subs = 256 sub-chunks/chunk. STATIC:
        // thread tid<256 owns sub-chunk tid (waves 0..3, wave-uniform guard,
        // compile-time indices -> register-resident).
        const int r0a = tid >> 2, c0a = tid & 3;
        const bool doA = (tid < 256);
        const float* asrc0 = x + (size_t)(row0 + r0a) * D_DIM + c0a * 8;
        const int adst0 = r0a * 32 + ((c0a + (r0a >> 1)) & 3) * 8;   // swizzled
        float4 areg00, areg01;

#define LOADA(kc) do { if (doA) { \
        areg00 = *reinterpret_cast<const float4*>(asrc0 + (kc));     \
        areg01 = *reinterpret_cast<const float4*>(asrc0 + (kc) + 4); \
        } } while (0)

#define WRITEA(Ab) do { if (doA) \
        *reinterpret_cast<uint4*>((Ab) + adst0) = cvt8u(areg00, areg01); \
        } while (0)

#define LOAD_AFR(m) { const int row_ = (m) * 16 + l15; \
        const int p_ = (quad + (row_ >> 1)) & 3; \
        afr##m = *reinterpret_cast<const bf16x8*>(Ab_ + row_ * 32 + p_ * 8); }
#define LOAD_BFR(n) { const int row_ = (nf * NTPW + (n)) * 16 + l15; \
        const int p_ = (quad + (row_ >> 1)) & 3; \
        bfr##n = *reinterpret_cast<const bf16x8*>(Bb_ + row_ * 32 + p_ * 8); }

        // prologue: stage chunk 0 into buffer 0
        LOADA(0);
        BLOAD(0);
        WRITEA(Abuf[0]);
        BWRITE(Bbuf[0]);

        #pragma unroll 1
        for (int c = 0; c < NCHUNK; ++c) {
            const int cur = c & 1;
            const unsigned short* Ab_ = Abuf[cur];
            const unsigned short* Bb_ = Bbuf[cur];
            __syncthreads();            // buf[cur] writes visible; buf^1 free
            if (c + 1 < NCHUNK) {
                LOADA((c + 1) * BK);    // globals fly over compute
                BLOAD((c + 1) * BK);
            }
            {
                bf16x8 afr0, afr1, afr2, afr3;
                bf16x8 bfr0, bfr1, bfr2, bfr3, bfr4;
                LOAD_AFR(0) LOAD_AFR(1) LOAD_AFR(2) LOAD_AFR(3)
                LOAD_BFR(0) LOAD_BFR(1) LOAD_BFR(2) LOAD_BFR(3) LOAD_BFR(4)
                FOR_MN(MFMA_MN)
            }
            if (c + 1 < NCHUNK) {       // cvt + LDS writes after compute
                WRITEA(Abuf[1 - cur]);
                BWRITE(Bbuf[1 - cur]);
            }
        }
    } else {
        // fallback: both fp32, plain loop (correctness insurance, no ws)
        const float* af = x + (size_t)(row0 + l15) * D_DIM + quad * 8;
        const float* bf32 = (const float*)b_any
                          + (size_t)((nf * NTPW) * 16 + l15) * D_DIM + quad * 8;
        for (int step = 0; step < 32; ++step) {
            const int off = step * 32;
            bf16x8 afr0, afr1, afr2, afr3;
            bf16x8 bfr0, bfr1, bfr2, bfr3, bfr4;
#define LOAD_AFR2(m) { \
            float4 a0_ = *reinterpret_cast<const float4*>(af + (size_t)(m) * 16 * D_DIM + off); \
            float4 a1_ = *reinterpret_cast<const float4*>(af + (size_t)(m) * 16 * D_DIM + off + 4); \
            afr##m = cvt8(a0_, a1_); }
#define LOAD_BFR2(n) { \
            float4 b0_ = *reinterpret_cast<const float4*>(bf32 + (size_t)(n) * 16 * D_DIM + off); \
            float4 b1_ = *reinterpret_cast<const float4*>(bf32 + (size_t)(n) * 16 * D_DIM + off + 4); \
            bfr##n = cvt8(b0_, b1_); }
            LOAD_AFR2(0) LOAD_AFR2(1) LOAD_AFR2(2) LOAD_AFR2(3)
            LOAD_BFR2(0) LOAD_BFR2(1) LOAD_BFR2(2) LOAD_BFR2(3) LOAD_BFR2(4)
            FOR_MN(MFMA_MN)
        }
    }

    // ---- epilogue ----
    // C/D layout: col = l15 (within tile), row = quad*4 + reg   [m89/m91]
    const float fcw0 = fcw[l15 & 3];        // fc_w[0][k], k = col&3
    const float fcw1 = fcw[4 + (l15 & 3)];  // fc_w[1][k]

#define PRE_N(n) \
    const float bias##n = b1[(nf * NTPW + (n)) * 16 + l15]; \
    const float tw##n   = fw[((nf * NTPW + (n)) * 16 + l15) >> 2];
    PRE_N(0) PRE_N(1) PRE_N(2) PRE_N(3) PRE_N(4)

    // per (m,r): q = sum over n of fw[t]*sigmoid(split)*S ; then 16-lane sum.
    // k-sum S: lanes ^1,^2 (l15 bits 0-1 are k within tree).
#define EPI_TERM(m,r,n) { \
        const float split_ = acc##m##n[r] + bias##n; \
        float s_ = split_; \
        s_ += __shfl_xor(s_, 1); \
        s_ += __shfl_xor(s_, 2); \
        const float leaf_ = 1.0f / (1.0f + __expf(-split_)); \
        const float val_ = tw##n * leaf_ * s_; \
        q0 += val_ * fcw0; q1 += val_ * fcw1; }

#define EPI_ONE(m,r) { \
        float q0 = 0.f, q1 = 0.f; \
        EPI_TERM(m,r,0) EPI_TERM(m,r,1) EPI_TERM(m,r,2) \
        EPI_TERM(m,r,3) EPI_TERM(m,r,4) \
        q0 += __shfl_xor(q0, 1); q0 += __shfl_xor(q0, 2); \
        q0 += __shfl_xor(q0, 4); q0 += __shfl_xor(q0, 8); \
        q1 += __shfl_xor(q1, 1); q1 += __shfl_xor(q1, 2); \
        q1 += __shfl_xor(q1, 4); q1 += __shfl_xor(q1, 8); \
        const int row_ = (m) * 16 + quad * 4 + (r);           /* 0..63 */ \
        if (l15 == 0) Pbuf[(row_ * NTPW + nf) * 2 + 0] = q0; \
        if (l15 == 1) Pbuf[(row_ * NTPW + nf) * 2 + 1] = q1; }

#define EPI_M(m) EPI_ONE(m,0) EPI_ONE(m,1) EPI_ONE(m,2) EPI_ONE(m,3)
    EPI_M(0) EPI_M(1) EPI_M(2) EPI_M(3)

    __syncthreads();

    if (tid < 2 * BM) {
        const int r = tid >> 1, j = tid & 1;
        float s = fcb[j];
        #pragma unroll
        for (int w = 0; w < NTPW; ++w)
            s += Pbuf[(r * NTPW + w) * 2 + j];
        out[(row0 + r) * 2 + j] = s;
    }
}

extern "C" void kernel_launch(void* const* d_in, const int* in_sizes, int n_in,
                              void* d_out, int out_size, void* d_ws, size_t ws_size,
                              hipStream_t stream) {
    const float* x   = (const float*)d_in[0];
    const float* W1  = (const float*)d_in[1];
    const float* b1  = (const float*)d_in[2];
    const float* fw  = (const float*)d_in[3];
    const float* fcw = (const float*)d_in[4];
    const float* fcb = (const float*)d_in[5];
    float* out = (float*)d_out;

    const size_t w1_elems = (size_t)N_COLS * D_DIM;   // 409,600
    if (ws_size >= w1_elems * sizeof(unsigned short)) {
        unsigned short* w1b = (unsigned short*)d_ws;
        cvt_f32_bf16_kernel<<<(int)(w1_elems / 2048), 256, 0, stream>>>(W1, w1b);
        xgb_v11<0><<<B_ROWS / BM, THREADS, 0, stream>>>(
            x, (const void*)w1b, b1, fw, fcw, fcb, out);
    } else {
        xgb_v11<2><<<B_ROWS / BM, THREADS, 0, stream>>>(
            x, (const void*)W1, b1, fw, fcw, fcb, out);
    }
}